// Round 7
// baseline (2161.536 us; speedup 1.0000x reference)
//
#include <hip/hip_runtime.h>

#define BN 16384
#define TT 128
#define MM 4
#define SS 12
#define BLOCK 64

// R13 = R0 (792us champion, 4 lanes/series posterior form) with the LDS
// U-transpose replaced by quad-DPP broadcasts in GEMM2.
//   - R0's tser round-trip (36 ds_write + wave_barrier + 36 ds_read + 144
//     F-reads, all per step) was the kernel's bank-conflict source (1.9e7)
//     and a hard serialization point. After GEMM1 each lane already holds
//     U[:, col0..col0+2] in registers; GEMM2's U[s][3q+kk] operands come
//     from quad sub-lane q via dpp broadcast (VALU pipe, no barrier).
//   - GEMM2 F-reads drop 144 -> 36 (9 per q-block, reused across rows).
//   - No LDS writes, no barriers anywhere in the t-loop.
// Session toolchain ledger: budget = 256/min_waves (launch_bounds or
// waves_per_eu min); waves_per_eu max ALSO caps runtime residency (R6:
// max=1 -> 11.6% occupancy despite 2048-wave grid). Octet TLP arc dead:
// 1.7x intrinsic overhead (R6) kills the 2x occupancy win.

// quad_perm ctrl: broadcast from sub-lane R -> R*0x55; xor1 -> 0xB1; xor2 -> 0x4E
template<int CTRL>
__device__ __forceinline__ float dpp32(float v) {
    union { int i; float f; } u, o;
    u.f = v;
    o.i = __builtin_amdgcn_update_dpp(0, u.i, CTRL, 0xF, 0xF, true);
    return o.f;
}
template<int CTRL>
__device__ __forceinline__ double dpp64(double v) {
    union { double d; int i[2]; } u, o;
    u.d = v;
    o.i[0] = __builtin_amdgcn_update_dpp(0, u.i[0], CTRL, 0xF, 0xF, true);
    o.i[1] = __builtin_amdgcn_update_dpp(0, u.i[1], CTRL, 0xF, 0xF, true);
    return o.d;
}
__device__ __forceinline__ double qsum(double v) {  // sum over the quad
    v += dpp64<0xB1>(v);
    v += dpp64<0x4E>(v);
    return v;
}

// GEMM2 accumulation from quad sub-lane CTRL's U columns (k = KOFF..KOFF+2).
// 6-row chunks keep the broadcast transient at 18 doubles.
template<int CTRL, int KOFF>
__device__ __forceinline__ void g2_accum(double (&P)[SS][3], const double (&U)[SS][3],
                                         const double* __restrict__ Fd, int col0) {
    double fq[3][3];
#pragma unroll
    for (int jj = 0; jj < 3; ++jj)
#pragma unroll
        for (int kk = 0; kk < 3; ++kk)
            fq[jj][kk] = Fd[(col0 + jj) * SS + KOFF + kk];
#pragma unroll
    for (int sh = 0; sh < 2; ++sh) {
        double Uq[6][3];
#pragma unroll
        for (int ii = 0; ii < 6; ++ii)
#pragma unroll
            for (int kk = 0; kk < 3; ++kk)
                Uq[ii][kk] = dpp64<CTRL>(U[sh * 6 + ii][kk]);
#pragma unroll
        for (int s = 0; s < 6; ++s)
#pragma unroll
            for (int jj = 0; jj < 3; ++jj)
#pragma unroll
                for (int kk = 0; kk < 3; ++kk)
                    P[sh * 6 + s][jj] += Uq[s][kk] * fq[jj][kk];
    }
}

__global__ __launch_bounds__(BLOCK, 1) void kf_kernel(
    const float* __restrict__ inp,   // [B][T][M]
    const float* __restrict__ Fm,    // [S][S]
    const float* __restrict__ Hm,    // [M][S]
    const float* __restrict__ Qm,    // [S][S]
    const float* __restrict__ Rm,    // [M][M]
    const float* __restrict__ m0p,   // [B][S]
    const float* __restrict__ P0p,   // [B][S][S]
    float* __restrict__ outp)        // [T][B][M]
{
    __shared__ double Fd[SS * SS];
    __shared__ double Hd[MM * SS];
    __shared__ double Qd[SS * SS];
    __shared__ double Rd[MM * MM];

    const int tid  = threadIdx.x;
    const int gid  = blockIdx.x * BLOCK + tid;
    const int b    = gid >> 2;        // series
    const int c    = gid & 3;         // quad sub-lane: owns P cols/rows {3c,3c+1,3c+2}
    const int col0 = 3 * c;

    for (int i = tid; i < SS * SS; i += BLOCK) {
        Fd[i] = (double)Fm[i];
        Qd[i] = (double)Qm[i];
    }
    if (tid < MM * SS) Hd[tid] = (double)Hm[tid];
    if (tid < MM * MM) Rd[tid] = (double)Rm[tid];

    // persistent per-lane state: full mean + own 3 columns of symmetric P
    double m[SS];
#pragma unroll
    for (int s = 0; s < SS; ++s) m[s] = (double)m0p[b * SS + s];

    double P[SS][3];
#pragma unroll
    for (int s = 0; s < SS; ++s)
#pragma unroll
        for (int jj = 0; jj < 3; ++jj)
            P[s][jj] = (double)P0p[b * SS * SS + s * SS + col0 + jj];

    const float* op = inp + b * (TT * MM) + c;  // own measurement stream
    float obn = op[0];

    __syncthreads();  // constants in LDS ready (once, outside the loop)

#pragma unroll 1
    for (int t = 0; t < TT; ++t) {
        // ---------- GEMM1: U[i][jj] = F[i,:] . P[:,col0+jj]  (registers) ----------
        double U[SS][3];
#pragma unroll
        for (int i = 0; i < SS; ++i) {
            double fr[SS];
#pragma unroll
            for (int s = 0; s < SS; ++s) fr[s] = Fd[i * SS + s];
            double u0 = 0.0, u1 = 0.0, u2 = 0.0;
#pragma unroll
            for (int s = 0; s < SS; ++s) {
                u0 += fr[s] * P[s][0];
                u1 += fr[s] * P[s][1];
                u2 += fr[s] * P[s][2];
            }
            U[i][0] = u0; U[i][1] = u1; U[i][2] = u2;
        }

        // ---------- own 3 rows of predicted mean: mvl[jj] = F[3c+jj,:] . m ----------
        double mvl[3];
#pragma unroll
        for (int jj = 0; jj < 3; ++jj) {
            double a = 0.0;
#pragma unroll
            for (int s = 0; s < SS; ++s) a += Fd[(col0 + jj) * SS + s] * m[s];
            mvl[jj] = a;
        }

        // ---------- GEMM2: P <- Q + U * F^T via quad DPP broadcasts ----------
        // (U[s][3q+kk] lives on quad sub-lane q; no LDS, no barrier)
#pragma unroll
        for (int s = 0; s < SS; ++s)
#pragma unroll
            for (int jj = 0; jj < 3; ++jj)
                P[s][jj] = Qd[s * SS + col0 + jj];

        g2_accum<0x00, 0>(P, U, Fd, col0);
        g2_accum<0x55, 3>(P, U, Fd, col0);
        g2_accum<0xAA, 6>(P, U, Fd, col0);
        g2_accum<0xFF, 9>(P, U, Fd, col0);

        // ---------- y[n] via quad DPP butterfly of partials ----------
        double y[MM];
#pragma unroll
        for (int n = 0; n < MM; ++n) {
            double py = Hd[n * SS + col0 + 0] * mvl[0]
                      + Hd[n * SS + col0 + 1] * mvl[1]
                      + Hd[n * SS + col0 + 2] * mvl[2];
            y[n] = qsum(py);
        }
        double ysel = (c & 2) ? ((c & 1) ? y[3] : y[2]) : ((c & 1) ? y[1] : y[0]);
        outp[t * (BN * MM) + b * MM + c] = (float)ysel;

        float obc = obn;
        if (t + 1 < TT) obn = op[(t + 1) * MM];  // prefetch next obs

        // residuals all-local (obs shared by 4 cheap b32 DPP broadcasts)
        double r[MM];
        r[0] = (double)dpp32<0x00>(obc) - y[0];
        r[1] = (double)dpp32<0x55>(obc) - y[1];
        r[2] = (double)dpp32<0xAA>(obc) - y[2];
        r[3] = (double)dpp32<0xFF>(obc) - y[3];

        // ---------- HP = H * P_prior (local cols) ----------
        double HPl[MM][3];
#pragma unroll
        for (int n = 0; n < MM; ++n) {
            double h0 = 0.0, h1 = 0.0, h2 = 0.0;
#pragma unroll
            for (int s = 0; s < SS; ++s) {
                double hv = Hd[n * SS + s];
                h0 += hv * P[s][0]; h1 += hv * P[s][1]; h2 += hv * P[s][2];
            }
            HPl[n][0] = h0; HPl[n][1] = h1; HPl[n][2] = h2;
        }

        // ---------- innovation cov: local partial + quad DPP butterfly ----------
        double Su[10];
        {
            int u = 0;
#pragma unroll
            for (int n = 0; n < MM; ++n)
#pragma unroll
                for (int t2 = 0; t2 < MM; ++t2) {
                    if (t2 < n) continue;
                    double acc = HPl[n][0] * Hd[t2 * SS + col0 + 0]
                               + HPl[n][1] * Hd[t2 * SS + col0 + 1]
                               + HPl[n][2] * Hd[t2 * SS + col0 + 2];
                    Su[u] = qsum(acc) + Rd[n * MM + t2];
                    ++u;
                }
        }
        double s00 = Su[0], s01 = Su[1], s02 = Su[2], s03 = Su[3];
        double s11 = Su[4], s12 = Su[5], s13 = Su[6];
        double s22 = Su[7], s23 = Su[8], s33 = Su[9];

        // ---------- symmetric 4x4 inverse via 2x2 Schur (fp64) ----------
        double ra   = 1.0 / (s00 * s11 - s01 * s01);
        double ai00 = s11 * ra, ai01 = -s01 * ra, ai11 = s00 * ra;
        double w00 = ai00 * s02 + ai01 * s12;
        double w01 = ai00 * s03 + ai01 * s13;
        double w10 = ai01 * s02 + ai11 * s12;
        double w11 = ai01 * s03 + ai11 * s13;
        double e00 = s22 - (s02 * w00 + s12 * w10);
        double e01 = s23 - (s02 * w01 + s12 * w11);
        double e11 = s33 - (s03 * w01 + s13 * w11);
        double rmm = 1.0 / (e00 * e11 - e01 * e01);
        double q22 = e11 * rmm, q23 = -e01 * rmm, q33 = e00 * rmm;
        double x00 = w00 * q22 + w01 * q23;
        double x01 = w00 * q23 + w01 * q33;
        double x10 = w10 * q22 + w11 * q23;
        double x11 = w10 * q23 + w11 * q33;
        double q00 = ai00 + x00 * w00 + x01 * w01;
        double q01 = ai01 + x00 * w10 + x01 * w11;
        double q11 = ai11 + x10 * w10 + x11 * w11;
        double Qi[MM][MM] = {
            { q00,  q01,  -x00, -x01 },
            { q01,  q11,  -x10, -x11 },
            { -x00, -x10,  q22,  q23 },
            { -x01, -x11,  q23,  q33 }
        };

        // ---------- z = Sinv r ; mean update (no K materialized) ----------
        double z0 = Qi[0][0] * r[0] + Qi[0][1] * r[1] + Qi[0][2] * r[2] + Qi[0][3] * r[3];
        double z1 = Qi[1][0] * r[0] + Qi[1][1] * r[1] + Qi[1][2] * r[2] + Qi[1][3] * r[3];
        double z2 = Qi[2][0] * r[0] + Qi[2][1] * r[1] + Qi[2][2] * r[2] + Qi[2][3] * r[3];
        double z3 = Qi[3][0] * r[0] + Qi[3][1] * r[1] + Qi[3][2] * r[2] + Qi[3][3] * r[3];

        double pm[3];  // posterior mean, own 3 states
#pragma unroll
        for (int jj = 0; jj < 3; ++jj)
            pm[jj] = mvl[jj] + HPl[0][jj] * z0 + HPl[1][jj] * z1
                   + HPl[2][jj] * z2 + HPl[3][jj] * z3;

        // all-gather posterior mean via DPP broadcasts (state k lives on lane k/3)
        m[0]  = dpp64<0x00>(pm[0]);  m[1]  = dpp64<0x00>(pm[1]);  m[2]  = dpp64<0x00>(pm[2]);
        m[3]  = dpp64<0x55>(pm[0]);  m[4]  = dpp64<0x55>(pm[1]);  m[5]  = dpp64<0x55>(pm[2]);
        m[6]  = dpp64<0xAA>(pm[0]);  m[7]  = dpp64<0xAA>(pm[1]);  m[8]  = dpp64<0xAA>(pm[2]);
        m[9]  = dpp64<0xFF>(pm[0]);  m[10] = dpp64<0xFF>(pm[1]);  m[11] = dpp64<0xFF>(pm[2]);

        // ---------- covariance update: P -= (HP)^T Sinv (HP) ----------
        double G[MM][3];  // G = Sinv * HP (local cols)
#pragma unroll
        for (int n = 0; n < MM; ++n)
#pragma unroll
            for (int jj = 0; jj < 3; ++jj)
                G[n][jj] = Qi[n][0] * HPl[0][jj] + Qi[n][1] * HPl[1][jj]
                         + Qi[n][2] * HPl[2][jj] + Qi[n][3] * HPl[3][jj];

        // rows 3q+jr gathered from sub-lane q via DPP broadcast
#pragma unroll
        for (int jr = 0; jr < 3; ++jr) {
            {
                double h0 = dpp64<0x00>(HPl[0][jr]), h1 = dpp64<0x00>(HPl[1][jr]);
                double h2 = dpp64<0x00>(HPl[2][jr]), h3 = dpp64<0x00>(HPl[3][jr]);
#pragma unroll
                for (int jj = 0; jj < 3; ++jj)
                    P[jr][jj] -= h0 * G[0][jj] + h1 * G[1][jj] + h2 * G[2][jj] + h3 * G[3][jj];
            }
            {
                double h0 = dpp64<0x55>(HPl[0][jr]), h1 = dpp64<0x55>(HPl[1][jr]);
                double h2 = dpp64<0x55>(HPl[2][jr]), h3 = dpp64<0x55>(HPl[3][jr]);
#pragma unroll
                for (int jj = 0; jj < 3; ++jj)
                    P[3 + jr][jj] -= h0 * G[0][jj] + h1 * G[1][jj] + h2 * G[2][jj] + h3 * G[3][jj];
            }
            {
                double h0 = dpp64<0xAA>(HPl[0][jr]), h1 = dpp64<0xAA>(HPl[1][jr]);
                double h2 = dpp64<0xAA>(HPl[2][jr]), h3 = dpp64<0xAA>(HPl[3][jr]);
#pragma unroll
                for (int jj = 0; jj < 3; ++jj)
                    P[6 + jr][jj] -= h0 * G[0][jj] + h1 * G[1][jj] + h2 * G[2][jj] + h3 * G[3][jj];
            }
            {
                double h0 = dpp64<0xFF>(HPl[0][jr]), h1 = dpp64<0xFF>(HPl[1][jr]);
                double h2 = dpp64<0xFF>(HPl[2][jr]), h3 = dpp64<0xFF>(HPl[3][jr]);
#pragma unroll
                for (int jj = 0; jj < 3; ++jj)
                    P[9 + jr][jj] -= h0 * G[0][jj] + h1 * G[1][jj] + h2 * G[2][jj] + h3 * G[3][jj];
            }
        }
    }
}

extern "C" void kernel_launch(void* const* d_in, const int* in_sizes, int n_in,
                              void* d_out, int out_size, void* d_ws, size_t ws_size,
                              hipStream_t stream) {
    const float* inp = (const float*)d_in[0];
    const float* F   = (const float*)d_in[1];
    const float* H   = (const float*)d_in[2];
    const float* Q   = (const float*)d_in[3];
    const float* R   = (const float*)d_in[4];
    const float* m0  = (const float*)d_in[5];
    const float* P0  = (const float*)d_in[6];
    float* out = (float*)d_out;

    dim3 grid((BN * MM) / BLOCK), block(BLOCK);
    hipLaunchKernelGGL(kf_kernel, grid, block, 0, stream,
                       inp, F, H, Q, R, m0, P0, out);
}